// Round 7
// baseline (979.645 us; speedup 1.0000x reference)
//
#include <hip/hip_runtime.h>

typedef _Float16 f16x8 __attribute__((ext_vector_type(8)));
typedef _Float16 f16x4 __attribute__((ext_vector_type(4)));
typedef float f32x4 __attribute__((ext_vector_type(4)));

#define BN   65536   // B*N = 16*4096
#define MSZ  4096
#define TOPK 8

#define MFMA(a, b, c) __builtin_amdgcn_mfma_f32_16x16x32_f16(a, b, c, 0, 0, 0)

// ---------------------------------------------------------------------------
// Prep: fp32 -> fp16 flat convert (keys)
// ---------------------------------------------------------------------------
__global__ void cvt_f16(const float* __restrict__ src, _Float16* __restrict__ dst,
                        int n) {
    int i = blockIdx.x * 256 + threadIdx.x;
    if (i < n) dst[i] = (_Float16)src[i];
}

// ---------------------------------------------------------------------------
// Prep: dst[n*K + k] = (f16)src[k*N + n]
// ---------------------------------------------------------------------------
__global__ void cvt_transpose(const float* __restrict__ src, _Float16* __restrict__ dst,
                              int K, int N) {
    int i = blockIdx.x * 256 + threadIdx.x;
    if (i < K * N) {
        int k = i / N, n = i - k * N;
        dst[n * K + k] = (_Float16)src[i];
    }
}

// ---------------------------------------------------------------------------
// Packed selection key: [31:12] = ordered-uint fp32 score (truncated),
// [11:0] = ~idx -> bigger = better, ties: lower idx wins (within truncation;
// resolved exactly at the fp32 reselect stage).
// ---------------------------------------------------------------------------
__device__ __forceinline__ unsigned pack_key(float s, unsigned inv12) {
    unsigned u = __float_as_uint(s);
    unsigned m = (unsigned)(((int)u) >> 31) | 0x80000000u;
    return ((u ^ m) & 0xFFFFF000u) | inv12;
}

__device__ __forceinline__ unsigned umaxu(unsigned a, unsigned b) { return a > b ? a : b; }
__device__ __forceinline__ unsigned uminu(unsigned a, unsigned b) { return a < b ? a : b; }

// Branchless sorted-desc insert: 2 VALU per level (v_max_u32 + v_min_u32).
template <int N>
__device__ __forceinline__ void ins(unsigned* t, unsigned key) {
#pragma unroll
    for (int p = N - 1; p > 0; --p)
        t[p] = uminu(t[p - 1], umaxu(t[p], key));
    t[0] = umaxu(t[0], key);
}

// ---------------------------------------------------------------------------
// Fully fused: proj -> sim -> top-k -> softmax -> gather -> MLP1 -> MLP2.
// 32 rows / block, 256 threads. Sim loop: barrier-free, double-buffered key
// prefetch, register top-5 per (row,slice) stream. Merge -> 12-candidate pool
// per row -> exact fp32 rescore + top-8 reselect -> softmax.
// ---------------------------------------------------------------------------
__global__ __launch_bounds__(256, 2) void fused_all(
        const float*    __restrict__ query,   // BN x 256 fp32
        const _Float16* __restrict__ keysH,   // 4096 x 256 f16 (ws)
        const float*    __restrict__ vals,    // 4096 x 256 fp32
        const _Float16* __restrict__ WqT,     // 256 x 256 f16 (ws^T)
        const float*    __restrict__ bq,
        const _Float16* __restrict__ W1T,     // 256 x 512 f16 (ws^T)
        const float*    __restrict__ b1,
        const _Float16* __restrict__ W2T,     // 256 x 256 f16 (ws^T)
        const float*    __restrict__ b2,
        float* __restrict__ out)              // BN x 256 fp32
{
    constexpr int ROWS = 32;
    __shared__ __attribute__((aligned(16))) _Float16 AA[ROWS][520];  // 33280 B
    __shared__ __attribute__((aligned(16))) unsigned Ubuf[4096];     // 16384 B
    __shared__ int Pi[ROWS][12];                                     // 1536 B

    float* Sc  = (float*)Ubuf;            // [32][12] overlay (post-merge)
    float* FsU = (float*)(Ubuf + 1024);   // [32][8]
    int*   FiU = (int*)(Ubuf + 1536);     // [32][8]

    const int tid  = threadIdx.x;
    const int lane = tid & 63, quad = lane >> 4, l16 = lane & 15, wave = tid >> 6;
    const size_t row0 = (size_t)blockIdx.x * ROWS;

    // ---- P0: stage 32 query rows (fp32 -> f16) into AA[:, 0:256) ----
    for (int v = tid; v < 2048; v += 256) {
        int r = v >> 6, c = (v & 63) * 4;
        float4 f = *(const float4*)(query + (row0 + r) * 256 + c);
        f16x4 h = {(_Float16)f.x, (_Float16)f.y, (_Float16)f.z, (_Float16)f.w};
        *(f16x4*)&AA[r][c] = h;
    }
    __syncthreads();

    // ---- P1: qproj = query @ Wq + bq -> AA[:, 256:512) ----
    {
        f32x4 acc[2][4];
#pragma unroll
        for (int rt = 0; rt < 2; ++rt)
#pragma unroll
            for (int nt = 0; nt < 4; ++nt)
                acc[rt][nt] = (f32x4){0.f, 0.f, 0.f, 0.f};
#pragma unroll
        for (int kf = 0; kf < 8; ++kf) {
            f16x8 a0 = *(const f16x8*)&AA[l16][kf * 32 + quad * 8];
            f16x8 a1 = *(const f16x8*)&AA[l16 + 16][kf * 32 + quad * 8];
#pragma unroll
            for (int nt = 0; nt < 4; ++nt) {
                int n0 = wave * 16 + nt * 64;
                f16x8 b = *(const f16x8*)(WqT + (size_t)(n0 + l16) * 256 + kf * 32 + quad * 8);
                acc[0][nt] = MFMA(a0, b, acc[0][nt]);
                acc[1][nt] = MFMA(a1, b, acc[1][nt]);
            }
        }
#pragma unroll
        for (int nt = 0; nt < 4; ++nt) {
            int col = wave * 16 + nt * 64 + l16;
            float bv = bq[col];
#pragma unroll
            for (int rt = 0; rt < 2; ++rt)
#pragma unroll
                for (int r = 0; r < 4; ++r)
                    AA[rt * 16 + quad * 4 + r][256 + col] = (_Float16)(acc[rt][nt][r] + bv);
        }
    }
    __syncthreads();

    // ---- P2: sim loop — barrier-free, double-buffered prefetch ----
    f16x8 af0[8], af1[8];
#pragma unroll
    for (int nk = 0; nk < 8; ++nk) {
        af0[nk] = *(const f16x8*)&AA[l16][256 + nk * 32 + quad * 8];
        af1[nk] = *(const f16x8*)&AA[l16 + 16][256 + nk * 32 + quad * 8];
    }

    unsigned tk[8][5];   // streams: rows quad*4+r (0..3), 16+quad*4+r (4..7)
#pragma unroll
    for (int s = 0; s < 8; ++s)
#pragma unroll
        for (int e = 0; e < 5; ++e) tk[s][e] = 0u;

    {
        const int colbase = wave * 16 + l16;
        const _Float16* bp = keysH + (size_t)colbase * 256 + quad * 8;
        f16x8 ba[8], bb[8];
#pragma unroll
        for (int nk = 0; nk < 8; ++nk) ba[nk] = *(const f16x8*)(bp + nk * 32);

        for (int m0 = 0; m0 < MSZ; m0 += 128) {
            // prefetch chunk m0+64 (reads past keys end land in WqT — valid mem)
            const _Float16* bp1 = bp + 64 * 256;
#pragma unroll
            for (int nk = 0; nk < 8; ++nk) bb[nk] = *(const f16x8*)(bp1 + nk * 32);

            {   // compute chunk m0 with ba
                f32x4 a0 = {0.f, 0.f, 0.f, 0.f}, a1 = {0.f, 0.f, 0.f, 0.f};
#pragma unroll
                for (int nk = 0; nk < 8; ++nk) {
                    a0 = MFMA(af0[nk], ba[nk], a0);
                    a1 = MFMA(af1[nk], ba[nk], a1);
                }
                unsigned inv12 = (~(unsigned)(m0 + colbase)) & 0xFFFu;
#pragma unroll
                for (int r = 0; r < 4; ++r) ins<5>(tk[r],     pack_key(a0[r], inv12));
#pragma unroll
                for (int r = 0; r < 4; ++r) ins<5>(tk[4 + r], pack_key(a1[r], inv12));
            }

            // prefetch chunk m0+128
            bp += 128 * 256;
#pragma unroll
            for (int nk = 0; nk < 8; ++nk) ba[nk] = *(const f16x8*)(bp + nk * 32);

            {   // compute chunk m0+64 with bb
                f32x4 a0 = {0.f, 0.f, 0.f, 0.f}, a1 = {0.f, 0.f, 0.f, 0.f};
#pragma unroll
                for (int nk = 0; nk < 8; ++nk) {
                    a0 = MFMA(af0[nk], bb[nk], a0);
                    a1 = MFMA(af1[nk], bb[nk], a1);
                }
                unsigned inv12 = (~(unsigned)(m0 + 64 + colbase)) & 0xFFFu;
#pragma unroll
                for (int r = 0; r < 4; ++r) ins<5>(tk[r],     pack_key(a0[r], inv12));
#pragma unroll
                for (int r = 0; r < 4; ++r) ins<5>(tk[4 + r], pack_key(a1[r], inv12));
            }
        }
    }

    // ---- merge per quad-group: dump(5) -> 10->6 -> 24->12 -> 96->12 pool ----
    for (int g = 0; g < 4; ++g) {
        __syncthreads();                       // Ubuf reuse across groups
        if (quad == g) {
            int slice = wave * 16 + l16;
#pragma unroll
            for (int rl = 0; rl < 8; ++rl)
#pragma unroll
                for (int e = 0; e < 5; ++e)
                    Ubuf[(rl * 64 + slice) * 5 + e] = tk[rl][e];
        }
        __syncthreads();
        {   // stage1: 256 threads, merge 2 slices (10) -> top-6
            int rl = tid >> 5, part = tid & 31;
            unsigned s1[6];
#pragma unroll
            for (int e = 0; e < 6; ++e) s1[e] = 0u;
            for (int sl = 2 * part; sl < 2 * part + 2; ++sl)
#pragma unroll
                for (int e = 0; e < 5; ++e)
                    ins<6>(s1, Ubuf[(rl * 64 + sl) * 5 + e]);
#pragma unroll
            for (int e = 0; e < 6; ++e)
                Ubuf[2560 + (rl * 32 + part) * 6 + e] = s1[e];
        }
        __syncthreads();
        if (tid < 64) {   // stage2: merge 4 stage1 lists (24) -> top-12
            int rl = tid >> 3, p8 = tid & 7;
            unsigned s2[12];
#pragma unroll
            for (int e = 0; e < 12; ++e) s2[e] = 0u;
            for (int q = 0; q < 4; ++q)
#pragma unroll
                for (int e = 0; e < 6; ++e)
                    ins<12>(s2, Ubuf[2560 + (rl * 32 + p8 * 4 + q) * 6 + e]);
#pragma unroll
            for (int e = 0; e < 12; ++e)
                Ubuf[(rl * 8 + p8) * 12 + e] = s2[e];   // over dead dump region
        }
        __syncthreads();
        if (tid < 8) {    // stage3: merge 8 stage2 lists (96) -> pool of 12
            unsigned s3[12];
#pragma unroll
            for (int e = 0; e < 12; ++e) s3[e] = 0u;
            for (int i = 0; i < 96; ++i) ins<12>(s3, Ubuf[tid * 96 + i]);
            int row = (tid < 4) ? (g * 4 + tid) : (16 + g * 4 + (tid - 4));
#pragma unroll
            for (int c = 0; c < 12; ++c)
                Pi[row][c] = 4095 - (int)(s3[c] & 0xFFFu);
        }
    }
    __syncthreads();

    // ---- rescore pool in exact fp32 (f16 operands, fp32 accumulate) ----
    {
        int r = tid >> 3, j = tid & 7;
#pragma unroll
        for (int pass = 0; pass < 2; ++pass) {
            int c = j + pass * 8;
            if (c < 12) {
                int idx = Pi[r][c] & (MSZ - 1);
                const f16x8* kp = (const f16x8*)(keysH + (size_t)idx * 256);
                float s = 0.f;
#pragma unroll
                for (int v = 0; v < 32; ++v) {
                    f16x8 kv = kp[v];
                    f16x8 qv = *(const f16x8*)&AA[r][256 + v * 8];
#pragma unroll
                    for (int e = 0; e < 8; ++e) s += (float)qv[e] * (float)kv[e];
                }
                Sc[r * 12 + c] = s;
            }
        }
    }
    __syncthreads();

    // ---- exact top-8 reselect (score desc, idx asc) + softmax ----
    if (tid < ROWS) {
        int r = tid;
        float sc[12]; int id[12]; bool used[12];
#pragma unroll
        for (int c = 0; c < 12; ++c) {
            sc[c] = Sc[r * 12 + c]; id[c] = Pi[r][c]; used[c] = false;
        }
        float sel_s[8]; int sel_i[8];
#pragma unroll
        for (int k = 0; k < TOPK; ++k) {
            float bs = -INFINITY; int bi = 0x7fffffff; int bc = 0;
            for (int c = 0; c < 12; ++c) {
                if (!used[c] && (sc[c] > bs || (sc[c] == bs && id[c] < bi))) {
                    bs = sc[c]; bi = id[c]; bc = c;
                }
            }
            used[bc] = true; sel_s[k] = bs; sel_i[k] = bi;
        }
        float mx = sel_s[0];
        float w[8], z = 0.f;
#pragma unroll
        for (int k = 0; k < TOPK; ++k) { w[k] = __expf(sel_s[k] - mx); z += w[k]; }
        float inv = 1.f / z;
#pragma unroll
        for (int k = 0; k < TOPK; ++k) { FsU[r * 8 + k] = w[k] * inv; FiU[r * 8 + k] = sel_i[k]; }
    }
    __syncthreads();

    // ---- P3: weighted gather of values (fp32) -> AA[:, 256:512) ----
    {
        const int r = tid >> 3, f0 = (tid & 7) * 32;
        float rv[32];
#pragma unroll
        for (int t = 0; t < 32; ++t) rv[t] = 0.f;
        for (int jj = 0; jj < TOPK; ++jj) {
            float wgt = FsU[r * 8 + jj];
            int idx = FiU[r * 8 + jj] & (MSZ - 1);
            const float4* vp = (const float4*)(vals + (size_t)idx * 256 + f0);
#pragma unroll
            for (int vv = 0; vv < 8; ++vv) {
                float4 vb = vp[vv];
                rv[vv * 4 + 0] += wgt * vb.x;
                rv[vv * 4 + 1] += wgt * vb.y;
                rv[vv * 4 + 2] += wgt * vb.z;
                rv[vv * 4 + 3] += wgt * vb.w;
            }
        }
#pragma unroll
        for (int t = 0; t < 32; ++t) AA[r][256 + f0 + t] = (_Float16)rv[t];
    }
    __syncthreads();

    // ---- P4: h = relu([query|retrieved] @ W1 + b1) -> AA[:, 0:256) ----
    {
        f32x4 acc[2][4];
#pragma unroll
        for (int rt = 0; rt < 2; ++rt)
#pragma unroll
            for (int nt = 0; nt < 4; ++nt)
                acc[rt][nt] = (f32x4){0.f, 0.f, 0.f, 0.f};
#pragma unroll
        for (int kf = 0; kf < 16; ++kf) {
            f16x8 a0 = *(const f16x8*)&AA[l16][kf * 32 + quad * 8];
            f16x8 a1 = *(const f16x8*)&AA[l16 + 16][kf * 32 + quad * 8];
#pragma unroll
            for (int nt = 0; nt < 4; ++nt) {
                int n0 = wave * 16 + nt * 64;
                f16x8 b = *(const f16x8*)(W1T + (size_t)(n0 + l16) * 512 + kf * 32 + quad * 8);
                acc[0][nt] = MFMA(a0, b, acc[0][nt]);
                acc[1][nt] = MFMA(a1, b, acc[1][nt]);
            }
        }
        __syncthreads();  // drain AA reads before overwriting cols 0:256
#pragma unroll
        for (int nt = 0; nt < 4; ++nt) {
            int col = wave * 16 + nt * 64 + l16;
            float bv = b1[col];
#pragma unroll
            for (int rt = 0; rt < 2; ++rt)
#pragma unroll
                for (int r = 0; r < 4; ++r)
                    AA[rt * 16 + quad * 4 + r][col] =
                        (_Float16)fmaxf(acc[rt][nt][r] + bv, 0.f);
        }
    }
    __syncthreads();

    // ---- P5: out = h @ W2 + b2 -> global (fp32) ----
    {
        f32x4 acc[2][4];
#pragma unroll
        for (int rt = 0; rt < 2; ++rt)
#pragma unroll
            for (int nt = 0; nt < 4; ++nt)
                acc[rt][nt] = (f32x4){0.f, 0.f, 0.f, 0.f};
#pragma unroll
        for (int kf = 0; kf < 8; ++kf) {
            f16x8 a0 = *(const f16x8*)&AA[l16][kf * 32 + quad * 8];
            f16x8 a1 = *(const f16x8*)&AA[l16 + 16][kf * 32 + quad * 8];
#pragma unroll
            for (int nt = 0; nt < 4; ++nt) {
                int n0 = wave * 16 + nt * 64;
                f16x8 b = *(const f16x8*)(W2T + (size_t)(n0 + l16) * 256 + kf * 32 + quad * 8);
                acc[0][nt] = MFMA(a0, b, acc[0][nt]);
                acc[1][nt] = MFMA(a1, b, acc[1][nt]);
            }
        }
#pragma unroll
        for (int nt = 0; nt < 4; ++nt) {
            int col = wave * 16 + nt * 64 + l16;
            float bv = b2[col];
#pragma unroll
            for (int rt = 0; rt < 2; ++rt)
#pragma unroll
                for (int r = 0; r < 4; ++r)
                    out[(row0 + rt * 16 + quad * 4 + r) * 256 + col] =
                        acc[rt][nt][r] + bv;
        }
    }
}

// ---------------------------------------------------------------------------
extern "C" void kernel_launch(void* const* d_in, const int* in_sizes, int n_in,
                              void* d_out, int out_size, void* d_ws, size_t ws_size,
                              hipStream_t stream) {
    const float* query = (const float*)d_in[0];
    const float* keys  = (const float*)d_in[1];
    const float* vals  = (const float*)d_in[2];
    const float* Wq    = (const float*)d_in[3];
    const float* bq    = (const float*)d_in[4];
    const float* W1    = (const float*)d_in[5];
    const float* b1    = (const float*)d_in[6];
    const float* W2    = (const float*)d_in[7];
    const float* b2    = (const float*)d_in[8];
    float* out = (float*)d_out;

    // ws layout (f16): keysH 2 MB @ 0 | WqT 128K | W1T 256K | W2T 128K = 2.5 MB
    char* ws = (char*)d_ws;
    _Float16* keysH = (_Float16*)(ws);
    _Float16* WqT   = (_Float16*)(ws + 2097152);
    _Float16* W1T   = (_Float16*)(ws + 2097152 + 131072);
    _Float16* W2T   = (_Float16*)(ws + 2097152 + 131072 + 262144);

    cvt_f16<<<4096, 256, 0, stream>>>(keys, keysH, MSZ * 256);
    cvt_transpose<<<256, 256, 0, stream>>>(Wq, WqT, 256, 256);
    cvt_transpose<<<512, 256, 0, stream>>>(W1, W1T, 512, 256);
    cvt_transpose<<<256, 256, 0, stream>>>(W2, W2T, 256, 256);

    fused_all<<<BN / 32, 256, 0, stream>>>(query, keysH, vals, WqT, bq,
                                           W1T, b1, W2T, b2, out);
}